// Round 18
// baseline (106.970 us; speedup 1.0000x reference)
//
#include <hip/hip_runtime.h>
#include <hip/hip_bf16.h>

#define BATCH   16
#define NELEM   131072
#define PRE_NMS 2048
#define POST_NMS 512
#define NBKT    8192
#define NCH     32
#define NSB     256
#define CTHR    1024

// ws: hist [0,512K) | cntA @524288 | cntB @524352 | (gap) |
// candA [524544,786688) | candB [786688,1048832) | sortA [1048832,1310976) |
// boxg [1310976,1573120) | sortB [1573120,1704192)
#define OFF_CNTA  524288
#define OFF_CNTB  524352
#define OFF_ZERO  524416
#define OFF_CANDA 524544
#define OFF_CANDB 786688
#define OFF_SORT  1048832
#define OFF_BOXG  1310976
#define OFF_SORTB 1573120

typedef unsigned long long u64;
typedef unsigned int u32;
typedef unsigned short u16;

__device__ __forceinline__ u32 okey_f32(float f) {
  u32 u = __float_as_uint(f);
  return (u & 0x80000000u) ? ~u : (u | 0x80000000u);  // ascending uint == ascending float
}

// 32 blocks per image (512 total): 4096 elements each, float4 loads
__global__ __launch_bounds__(256) void hist_kernel(const float* __restrict__ obj,
                                                   u32* __restrict__ hist) {
  int b = blockIdx.x >> 5, q = blockIdx.x & 31;
  __shared__ u32 lh[NBKT];
  for (int i = threadIdx.x; i < NBKT; i += 256) lh[i] = 0u;
  __syncthreads();
  const float4* p4 = (const float4*)(obj + (size_t)b * NELEM + (size_t)q * 4096);
#pragma unroll
  for (int k = 0; k < 4; ++k) {
    float4 v = p4[threadIdx.x + k * 256];
    atomicAdd(&lh[okey_f32(v.x) >> 19], 1u);
    atomicAdd(&lh[okey_f32(v.y) >> 19], 1u);
    atomicAdd(&lh[okey_f32(v.z) >> 19], 1u);
    atomicAdd(&lh[okey_f32(v.w) >> 19], 1u);
  }
  __syncthreads();
  u32* gh = hist + (size_t)b * NBKT;
  for (int i = threadIdx.x; i < NBKT; i += 256) {
    u32 c = lh[i];
    if (c) atomicAdd(&gh[i], c);
  }
}

// collect with fused per-block cut computation; 64 blocks/image, float4 loads.
__global__ __launch_bounds__(256) void collect_kernel(
    const float* __restrict__ obj, const u32* __restrict__ hist,
    u32* __restrict__ cntA, u32* __restrict__ cntB,
    u64* __restrict__ candA, u64* __restrict__ candB) {
  int b = blockIdx.x >> 6, seg = blockIdx.x & 63;
  __shared__ u64 buf[2048];                  // A grows up, B grows down (16 KB)
  __shared__ u32 sa[256], sb[256];
  __shared__ u32 cutS;
  __shared__ u32 lA, lB, gA, gB;
  int t = threadIdx.x;

  // ---- redundant cut computation (identical math to old cut_kernel) ----
  {
    const u32* h = hist + (size_t)b * NBKT;
    u32 loc[32];
    u32 s = 0;
#pragma unroll
    for (int k = 0; k < 32; ++k) { loc[k] = h[t * 32 + k]; s += loc[k]; }
    sa[t] = s;
    if (t == 0) { lA = 0u; lB = 0u; }
    __syncthreads();
    u32* cur = sa; u32* nxt = sb;
    for (int d = 1; d < 256; d <<= 1) {       // inclusive suffix scan
      nxt[t] = cur[t] + ((t + d < 256) ? cur[t + d] : 0u);
      __syncthreads();
      u32* tmp = cur; cur = nxt; nxt = tmp;
    }
    u32 above = cur[t] - s;
    u32 run = above;
#pragma unroll
    for (int k = 31; k >= 0; --k) {           // high -> low buckets
      u32 prev = run; run += loc[k];
      // at chosen bucket: S(strictly above)=prev < 2048, S+T = run >= 2048
      if (prev < PRE_NMS && run >= PRE_NMS) cutS = (u32)(t * 32 + k);
    }
  }
  __syncthreads();
  u32 c = cutS;

  const float4* p4 = (const float4*)(obj + (size_t)b * NELEM + (size_t)seg * 2048);
#pragma unroll
  for (int k = 0; k < 2; ++k) {
    float4 v = p4[t + k * 256];
    int e0 = seg * 2048 + 4 * (t + k * 256);
    float vv[4] = {v.x, v.y, v.z, v.w};
#pragma unroll
    for (int j = 0; j < 4; ++j) {
      u32 ok = okey_f32(vv[j]);
      u32 bkt = ok >> 19;
      if (bkt >= c) {
        u64 key = ((u64)(~ok) << 32) | (u32)(e0 + j);
        if (bkt > c) buf[atomicAdd(&lA, 1u)] = key;
        else         buf[2047u - atomicAdd(&lB, 1u)] = key;
      }
    }
  }
  __syncthreads();
  if (t == 0) { gA = atomicAdd(&cntA[b], lA); gB = atomicAdd(&cntB[b], lB); }
  __syncthreads();
  u64* cbA = candA + (size_t)b * PRE_NMS;
  u64* cbB = candB + (size_t)b * PRE_NMS;
  for (u32 i = t; i < lA; i += 256) {
    u32 d = gA + i; if (d < 2048u) cbA[d] = buf[i];
  }
  for (u32 i = t; i < lB; i += 256) {
    u32 d = gB + i; if (d < 2048u) cbB[d] = buf[2047u - i];
  }
}

// EXACT f32-only replacement for: fdiv_rn(max(i,0), max(uni,1e-6)) > 0.5
// (proof in R3/R4: i > 0.5f*max(uni,1e-6) is bit-identical to the reference)
__device__ __forceinline__ bool iou_gt(float2 a, float wa, float2 b, float wb) {
  float i = __fsub_rn(fminf(a.y, b.y), fmaxf(a.x, b.x));
  float uni = __fsub_rn(__fadd_rn(wa, wb), i);
  return i > __fmul_rn(0.5f, fmaxf(uni, 1e-6f));
}

__device__ __forceinline__ float2 decode_one(const float2* __restrict__ d2,
                                             const float2* __restrict__ a2,
                                             size_t base, u32 idx, float img) {
  float2 dd = d2[base + idx];
  float2 aa = a2[base + idx];
  float aw = __fsub_rn(aa.y, aa.x);
  float ac = __fadd_rn(aa.x, __fmul_rn(0.5f, aw));
  float dw = fminf(dd.y, 4.0f);
  float pc = __fadd_rn(__fmul_rn(dd.x, aw), ac);
  float pw = __fmul_rn(expf(dw), aw);
  float hx = __fmul_rn(0.5f, pw);
  float x1 = fminf(fmaxf(__fsub_rn(pc, hx), 0.0f), img);
  float x2 = fminf(fmaxf(__fadd_rn(pc, hx), 0.0f), img);
  return make_float2(x1, x2);
}

__device__ __forceinline__ u64 shflx64(u64 v, int j) {
  int lo = __shfl_xor((int)(u32)v, j, 64);
  int hi = __shfl_xor((int)(u32)(v >> 32), j, 64);
  return ((u64)(u32)hi << 32) | (u64)(u32)lo;
}

__device__ __forceinline__ void wave_ce(u64& e, int i, int k, int j, int lane) {
  u64 o = shflx64(e, j);
  bool low = ((lane & j) == 0);
  bool up = ((i & k) == 0);
  u64 mn = (o < e) ? o : e;
  u64 mx = (o < e) ? e : o;
  e = (low == up) ? mn : mx;
}

__device__ __forceinline__ void reg_ce(u64& a, u64& b, bool up) {
  u64 mn = (b < a) ? b : a;
  u64 mx = (b < a) ? a : b;
  a = up ? mn : mx;
  b = up ? mx : mn;
}

__device__ __forceinline__ void lds_ce(u64& e, u64 o, bool low, bool up) {
  u64 mn = (o < e) ? o : e;
  u64 mx = (o < e) ? e : o;
  e = (low == up) ? mn : mx;
}

// 3 blocks per image: h<2 sort the two A-halves; h==2 sorts B's first 1024 keys.
__global__ __launch_bounds__(512) void sorthalf_kernel(
    const u32* __restrict__ cntA, const u32* __restrict__ cntB,
    const u64* __restrict__ candA, const u64* __restrict__ candB,
    u64* __restrict__ sortA, u64* __restrict__ sortB) {
  __shared__ u64 ping[1024], pong[1024];   // 16 KB
  int b = blockIdx.x / 3, h = blockIdx.x % 3;
  int t = threadIdx.x, lane = t & 63;
  const u64* src;
  u64* dst;
  u32 lim;
  if (h < 2) {
    u32 S = cntA[b]; if (S > 2047u) S = 2047u;
    src = candA + (size_t)b * PRE_NMS + h * 1024;
    lim = (S > (u32)(h * 1024)) ? (S - (u32)(h * 1024)) : 0u;
    dst = sortA + (size_t)b * PRE_NMS + h * 1024;
  } else {
    u32 T = cntB[b]; if (T > 1024u) T = 1024u;   // T>1024 handled by rankdec fallback
    src = candB + (size_t)b * PRE_NMS;
    lim = T;
    dst = sortB + (size_t)b * 1024;
  }
  u64 e0 = ((u32)t < lim) ? src[t] : ~0ull;
  u64 e1 = ((u32)(t + 512) < lim) ? src[t + 512] : ~0ull;
  for (int k = 2; k <= 64; k <<= 1)
    for (int j = k >> 1; j >= 1; j >>= 1) {
      wave_ce(e0, t, k, j, lane);
      wave_ce(e1, t + 512, k, j, lane);
    }
  int pp = 0;
  for (int k = 128; k <= 1024; k <<= 1) {
    for (int j = k >> 1; j >= 64; j >>= 1) {
      if (j == 512) {
        reg_ce(e0, e1, true);              // k==1024 only: up for both halves
      } else {
        u64* buf = (pp & 1) ? pong : ping; ++pp;
        buf[t] = e0; buf[t + 512] = e1;
        __syncthreads();
        u64 o0 = buf[t ^ j];
        u64 o1 = buf[(t ^ j) + 512];
        bool low = ((t & j) == 0);
        lds_ce(e0, o0, low, ((t) & k) == 0);
        lds_ce(e1, o1, low, (((t + 512) & k)) == 0);
      }
    }
    for (int j = 32; j >= 1; j >>= 1) {
      wave_ce(e0, t, k, j, lane);
      wave_ce(e1, t + 512, k, j, lane);
    }
  }
  dst[t] = e0; dst[t + 512] = e1;
}

__device__ __forceinline__ u32 lowerbound(const u64* arr, u32 n, u64 k) {
  u32 lo = 0, hi = n;
  while (lo < hi) { u32 mid = (lo + hi) >> 1; if (arr[mid] < k) lo = mid + 1; else hi = mid; }
  return lo;
}

// rank (merge for A, pre-sorted for B) + decode + scatter boxes: 4 blocks/image
__global__ __launch_bounds__(512) void rankdec_kernel(
    const float* __restrict__ delta, const float* __restrict__ anchor,
    const int* __restrict__ imgp,
    const u32* __restrict__ cntA, const u32* __restrict__ cntB,
    const u64* __restrict__ sortA, const u64* __restrict__ candB,
    const u64* __restrict__ sortB, float2* __restrict__ boxg) {
  __shared__ u64 half_[PRE_NMS];   // 16 KB
  __shared__ u64 bkeys[PRE_NMS];   // 16 KB (fallback path only)

  int b = blockIdx.x >> 2, q = blockIdx.x & 3;
  int t = threadIdx.x;
  u32 S = cntA[b]; if (S > 2047u) S = 2047u;
  u32 T = cntB[b]; if (T > 2048u) T = 2048u;
  const u64* sA = sortA + (size_t)b * PRE_NMS;
  const u64* cB = candB + (size_t)b * PRE_NMS;
  for (int i = t; i < PRE_NMS; i += 512) half_[i] = sA[i];
  if (T > 1024u) {
    for (int i = t; i < PRE_NMS; i += 512) bkeys[i] = cB[i];
  }
  __syncthreads();

  int iv = imgp[0];
  float img = (iv > 0 && iv < 1000000) ? (float)iv : __int_as_float(iv);
  const float2* d2 = (const float2*)delta;
  const float2* a2 = (const float2*)anchor;
  size_t base = (size_t)b * NELEM;
  float2* bg = boxg + (size_t)b * PRE_NMS;

  {
    int p = q * 512 + t;
    u64 k = half_[p];
    if (k != ~0ull) {
      u32 rank;
      if (p < 1024) rank = (u32)p + lowerbound(half_ + 1024, 1024, k);
      else          rank = (u32)(p - 1024) + lowerbound(half_, 1024, k);
      bg[rank] = decode_one(d2, a2, base, (u32)k, img);
    }
  }
  if (T <= 1024u) {
    u32 idx = (u32)(q * 512 + t);
    if (idx < T) {
      u64 k = sortB[(size_t)b * 1024 + idx];
      u32 pos = S + idx;
      if (pos < 2048u) bg[pos] = decode_one(d2, a2, base, (u32)k, img);
    }
  } else {
    u32 idx = (u32)(q * 512 + t);
    if (idx < T) {
      u64 k = bkeys[idx];
      u32 cnt = 0;
      for (u32 j = 0; j < T; ++j) cnt += (bkeys[j] < k) ? 1u : 0u;
      u32 pos = S + cnt;
      if (pos < 2048u) bg[pos] = decode_one(d2, a2, base, (u32)k, img);
    }
  }
}

// chain: R7's validated TWO-barrier scheme + cbox/cpid marking.
// BYTE-IDENTICAL to R17's validated chain_kernel — do not modify.
__global__ __launch_bounds__(CTHR) void chain_kernel(
    const int* __restrict__ imgp, const float2* __restrict__ boxg,
    float* __restrict__ out) {
  __shared__ float2 box[PRE_NMS];      // 16 KB
  __shared__ float2 cbox[PRE_NMS];     // 16 KB center-sorted boxes
  __shared__ u16 cpid[PRE_NMS];        // 4 KB original pos of center-sorted slot
  __shared__ u32 bincnt[NSB], binstart[NSB + 1], binfill[NSB];
  __shared__ u32 supm[64];
  __shared__ float2 wbox[64];
  __shared__ u32 wrange[64];
  __shared__ u32 nkeptS, LcntS;
  __shared__ u32 keepw[NCH * 2];
  __shared__ u32 wpre[65];

  int b = blockIdx.x, t = threadIdx.x;
  int wv = t >> 6, lane = t & 63;

  int iv = imgp[0];
  float img = (iv > 0 && iv < 1000000) ? (float)iv : __int_as_float(iv);
  float sbin = (float)NSB / img;

  const float2* bg = boxg + (size_t)b * PRE_NMS;
  float2 bx0 = bg[t];
  float2 bx1 = bg[t + 1024];
  float wa0 = __fsub_rn(bx0.y, bx0.x);
  float wa1 = __fsub_rn(bx1.y, bx1.x);
  box[t] = bx0;
  box[t + 1024] = bx1;
  if (t < NSB) { bincnt[t] = 0u; binfill[t] = 0u; }
  if (t < 64) supm[t] = 0u;
  if (t == 0) LcntS = 0u;
  float ca0 = __fmul_rn(0.5f, __fadd_rn(bx0.x, bx0.y));
  float ca1 = __fmul_rn(0.5f, __fadd_rn(bx1.x, bx1.y));
  int bi0 = (int)(ca0 * sbin); if (bi0 > NSB - 1) bi0 = NSB - 1;
  int bi1 = (int)(ca1 * sbin); if (bi1 > NSB - 1) bi1 = NSB - 1;
  __syncthreads();

  // spatial counting sort of candidate centers into 256 bins
  atomicAdd(&bincnt[bi0], 1u);
  atomicAdd(&bincnt[bi1], 1u);
  __syncthreads();
  if (wv == 0) {
    u32 c0 = bincnt[lane * 4 + 0], c1 = bincnt[lane * 4 + 1];
    u32 c2 = bincnt[lane * 4 + 2], c3 = bincnt[lane * 4 + 3];
    u32 ssum = c0 + c1 + c2 + c3;
    u32 inc = ssum;
    for (int d = 1; d < 64; d <<= 1) {
      u32 v = __shfl_up(inc, d);
      if (lane >= d) inc += v;
    }
    u32 excl = inc - ssum;
    binstart[lane * 4 + 0] = excl;
    binstart[lane * 4 + 1] = excl + c0;
    binstart[lane * 4 + 2] = excl + c0 + c1;
    binstart[lane * 4 + 3] = excl + c0 + c1 + c2;
    if (lane == 63) binstart[NSB] = inc;
  }
  __syncthreads();
  {
    u32 s0 = binstart[bi0] + atomicAdd(&binfill[bi0], 1u);
    cpid[s0] = (u16)t;           cbox[s0] = bx0;
    u32 s1 = binstart[bi1] + atomicAdd(&binfill[bi1], 1u);
    cpid[s1] = (u16)(t + 1024);  cbox[s1] = bx1;
  }

  // in-chunk 64x64 exact adjacency rows, kept in registers
  u64 m0 = 0ull, m1 = 0ull;
  {
    int c0 = wv * 64, c1 = (wv + 16) * 64;
    for (int j = 0; j < 64; ++j) {
      float2 bb0 = box[c0 + j];
      float2 bb1 = box[c1 + j];
      float w0 = __fsub_rn(bb0.y, bb0.x);
      float w1 = __fsub_rn(bb1.y, bb1.x);
      if ((j != lane) & iou_gt(bx0, wa0, bb0, w0)) m0 |= 1ull << j;
      if ((j != lane) & iou_gt(bx1, wa1, bb1, w1)) m1 |= 1ull << j;
    }
  }
  __syncthreads();   // cpid/cbox complete

  // greedy NMS: scan chunk -> parallel windowed marking (two barriers/chunk)
  for (int ch = 0; ch < NCH; ++ch) {
    if (wv == (ch & 15)) {
      u32 supw = supm[ch * 2 + (lane >> 5)];
      bool mysup = (supw >> (lane & 31)) & 1u;
      u64 s = __ballot(mysup);
      u64 rem = ~s;
      u64 kept = 0ull;
      u64 myrow = (ch < 16) ? m0 : m1;
      u32 mlo = (u32)myrow, mhi = (u32)(myrow >> 32);
      while (rem) {                    // visit kept candidates only
        int i = __builtin_ctzll(rem);
        kept |= 1ull << i;
        u32 rlo = (u32)__builtin_amdgcn_readlane((int)mlo, i);
        u32 rhi = (u32)__builtin_amdgcn_readlane((int)mhi, i);
        u64 row = ((u64)rhi << 32) | (u64)rlo;
        rem &= ~(row | (1ull << i));
      }
      if ((kept >> lane) & 1ull) {
        float2 mb = (ch < 16) ? bx0 : bx1;
        // IoU>0.5 => suppressed box's center lies in [x1,x2]; +-0.25 margin
        // absorbs all f32 rounding and bin quantization (conservative).
        float loc_ = fmaxf(__fsub_rn(mb.x, 0.25f), 0.0f);
        float hic_ = __fadd_rn(mb.y, 0.25f);
        int blo = (int)(loc_ * sbin); if (blo > NSB - 1) blo = NSB - 1;
        int bhi = (int)(hic_ * sbin); if (bhi > NSB - 1) bhi = NSB - 1;
        u32 lo = binstart[blo];
        u32 hi = binstart[bhi + 1];
        u32 li = (u32)__popcll(kept & ((1ull << lane) - 1ull));
        wbox[li] = mb;
        wrange[li] = (lo << 16) | hi;
      }
      if (lane == 0) {
        keepw[ch * 2]     = (u32)kept;
        keepw[ch * 2 + 1] = (u32)(kept >> 32);
        nkeptS = (u32)__popcll(kept);
        LcntS += (u32)__popcll(kept);
      }
    }
    __syncthreads();                   // (A) scan results visible
    if (LcntS >= POST_NMS) {
      // outputs fully determined by the first 512 kept: zero undecided chunks
      int w2 = (ch + 1) * 2 + t;
      if (w2 < NCH * 2) keepw[w2] = 0u;
      break;
    }
    u32 nk = nkeptS;
    u32 cmin = (u32)(ch + 1) * 64u;    // only undecided chunks need marks
    for (u32 k2 = (u32)wv; k2 < nk; k2 += 16u) {
      float2 kb = wbox[k2];
      u32 rng = wrange[k2];
      u32 lo = rng >> 16, hi = rng & 0xFFFFu;
      float wbk = __fsub_rn(kb.y, kb.x);
      for (u32 idx = lo + (u32)lane; idx < hi; idx += 64u) {
        float2 bp = cbox[idx];          // independent load
        u32 p = cpid[idx];              // independent load (no chain)
        if (p >= cmin) {
          float wp = __fsub_rn(bp.y, bp.x);
          if (iou_gt(bp, wp, kb, wbk))
            atomicOr(&supm[p >> 5], 1u << (p & 31));
        }
      }
    }
    __syncthreads();                   // (B) marking visible before next scan
  }
  __syncthreads();                     // keepw zeroing (early-exit) visible

  // stable partition: kept first (ascending), then unkept (ascending)
  if (wv == 0) {
    u32 wvv = keepw[lane];
    u32 pc = __popc(wvv);
    u32 inc = pc;
    for (int d = 1; d < 64; d <<= 1) {
      u32 v = __shfl_up(inc, d);
      if (lane >= d) inc += v;
    }
    wpre[lane] = inc - pc;
    if (lane == 63) wpre[64] = inc;
  }
  __syncthreads();
  u32 K = wpre[64];
  size_t selOff = (size_t)BATCH * POST_NMS * 2;
  size_t valOff = selOff + (size_t)BATCH * POST_NMS;
#pragma unroll
  for (int r = 0; r < 2; ++r) {
    int p = t + CTHR * r;
    u32 w = p >> 5, bit = p & 31;
    u32 wvv = keepw[w];
    bool kp = (wvv >> bit) & 1u;
    u32 kpref = wpre[w] + __popc(wvv & ((1u << bit) - 1u));
    u32 rr = kp ? kpref : (K + ((u32)p - kpref));
    if (rr < POST_NMS) {
      float2 bxo = kp ? box[p] : make_float2(0.0f, 0.0f);
      size_t ob = (size_t)b * POST_NMS + rr;
      out[ob * 2 + 0] = bxo.x;
      out[ob * 2 + 1] = bxo.y;
      out[selOff + ob] = (float)p;
      out[valOff + ob] = kp ? 1.0f : 0.0f;
    }
  }
}

extern "C" void kernel_launch(void* const* d_in, const int* in_sizes, int n_in,
                              void* d_out, int out_size, void* d_ws, size_t ws_size,
                              hipStream_t stream) {
  const float* obj    = (const float*)d_in[0];
  const float* delta  = (const float*)d_in[1];
  const float* anchor = (const float*)d_in[2];
  const int*   imgp   = (const int*)d_in[3];
  float* out = (float*)d_out;

  unsigned char* w = (unsigned char*)d_ws;
  u32* hist  = (u32*)(w);
  u32* cntA  = (u32*)(w + OFF_CNTA);
  u32* cntB  = (u32*)(w + OFF_CNTB);
  u64* candA = (u64*)(w + OFF_CANDA);
  u64* candB = (u64*)(w + OFF_CANDB);
  u64* sortA = (u64*)(w + OFF_SORT);
  float2* boxg = (float2*)(w + OFF_BOXG);
  u64* sortB = (u64*)(w + OFF_SORTB);

  hipMemsetAsync(w, 0, OFF_ZERO, stream);   // re-init hist + cnts every call

  hist_kernel<<<dim3(512), dim3(256), 0, stream>>>(obj, hist);
  collect_kernel<<<dim3(1024), dim3(256), 0, stream>>>(obj, hist, cntA, cntB, candA, candB);
  sorthalf_kernel<<<dim3(BATCH * 3), dim3(512), 0, stream>>>(cntA, cntB, candA, candB,
                                                             sortA, sortB);
  rankdec_kernel<<<dim3(BATCH * 4), dim3(512), 0, stream>>>(delta, anchor, imgp,
                                                            cntA, cntB, sortA, candB,
                                                            sortB, boxg);
  chain_kernel<<<dim3(BATCH), dim3(CTHR), 0, stream>>>(imgp, boxg, out);
}

// Round 19
// 100.652 us; speedup vs baseline: 1.0628x; 1.0628x over previous
//
#include <hip/hip_runtime.h>
#include <hip/hip_bf16.h>

#define BATCH   16
#define NELEM   131072
#define PRE_NMS 2048
#define POST_NMS 512
#define NBKT    8192
#define NCH     32
#define NSB     256
#define CTHR    1024

// ws: hist [0,512K) | cntA @524288 | cntB @524352 | (gap) |
// candA [524544,786688) | candB [786688,1048832) | sortA [1048832,1310976) |
// boxg [1310976,1573120) | sortB [1573120,1704192)
#define OFF_CNTA  524288
#define OFF_CNTB  524352
#define OFF_ZERO  524416
#define OFF_CANDA 524544
#define OFF_CANDB 786688
#define OFF_SORT  1048832
#define OFF_BOXG  1310976
#define OFF_SORTB 1573120

typedef unsigned long long u64;
typedef unsigned int u32;
typedef unsigned short u16;

__device__ __forceinline__ u32 okey_f32(float f) {
  u32 u = __float_as_uint(f);
  return (u & 0x80000000u) ? ~u : (u | 0x80000000u);  // ascending uint == ascending float
}

__global__ __launch_bounds__(256) void hist_kernel(const float* __restrict__ obj,
                                                   u32* __restrict__ hist) {
  int b = blockIdx.x >> 4, q = blockIdx.x & 15;   // 16 blocks per image
  __shared__ u32 lh[NBKT];
  for (int i = threadIdx.x; i < NBKT; i += 256) lh[i] = 0u;
  __syncthreads();
  const float4* p4 = (const float4*)(obj + (size_t)b * NELEM + (size_t)q * 8192);
#pragma unroll
  for (int k = 0; k < 8; ++k) {
    float4 v = p4[threadIdx.x + k * 256];
    atomicAdd(&lh[okey_f32(v.x) >> 19], 1u);
    atomicAdd(&lh[okey_f32(v.y) >> 19], 1u);
    atomicAdd(&lh[okey_f32(v.z) >> 19], 1u);
    atomicAdd(&lh[okey_f32(v.w) >> 19], 1u);
  }
  __syncthreads();
  u32* gh = hist + (size_t)b * NBKT;
  for (int i = threadIdx.x; i < NBKT; i += 256) {
    u32 c = lh[i];
    if (c) atomicAdd(&gh[i], c);
  }
}

// collect with fused per-block cut computation (cut_kernel launch eliminated).
__global__ __launch_bounds__(256) void collect_kernel(
    const float* __restrict__ obj, const u32* __restrict__ hist,
    u32* __restrict__ cntA, u32* __restrict__ cntB,
    u64* __restrict__ candA, u64* __restrict__ candB) {
  int b = blockIdx.x >> 5, seg = blockIdx.x & 31;
  __shared__ u64 buf[4096];                  // A grows up, B grows down (32 KB)
  __shared__ u32 sa[256], sb[256];
  __shared__ u32 cutS;
  __shared__ u32 lA, lB, gA, gB;
  int t = threadIdx.x;

  {
    const u32* h = hist + (size_t)b * NBKT;
    u32 loc[32];
    u32 s = 0;
#pragma unroll
    for (int k = 0; k < 32; ++k) { loc[k] = h[t * 32 + k]; s += loc[k]; }
    sa[t] = s;
    if (t == 0) { lA = 0u; lB = 0u; }
    __syncthreads();
    u32* cur = sa; u32* nxt = sb;
    for (int d = 1; d < 256; d <<= 1) {       // inclusive suffix scan
      nxt[t] = cur[t] + ((t + d < 256) ? cur[t + d] : 0u);
      __syncthreads();
      u32* tmp = cur; cur = nxt; nxt = tmp;
    }
    u32 above = cur[t] - s;
    u32 run = above;
#pragma unroll
    for (int k = 31; k >= 0; --k) {           // high -> low buckets
      u32 prev = run; run += loc[k];
      if (prev < PRE_NMS && run >= PRE_NMS) cutS = (u32)(t * 32 + k);
    }
  }
  __syncthreads();
  u32 c = cutS;

  const float* p = obj + (size_t)b * NELEM + (size_t)seg * 4096;
#pragma unroll
  for (int k = 0; k < 16; ++k) {
    int li = t + k * 256;
    u32 ok = okey_f32(p[li]);
    u32 bkt = ok >> 19;
    if (bkt >= c) {
      u64 key = ((u64)(~ok) << 32) | (u32)(seg * 4096 + li);
      if (bkt > c) buf[atomicAdd(&lA, 1u)] = key;
      else         buf[4095u - atomicAdd(&lB, 1u)] = key;
    }
  }
  __syncthreads();
  if (t == 0) { gA = atomicAdd(&cntA[b], lA); gB = atomicAdd(&cntB[b], lB); }
  __syncthreads();
  u64* cbA = candA + (size_t)b * PRE_NMS;
  u64* cbB = candB + (size_t)b * PRE_NMS;
  for (u32 i = t; i < lA; i += 256) {
    u32 d = gA + i; if (d < 2048u) cbA[d] = buf[i];
  }
  for (u32 i = t; i < lB; i += 256) {
    u32 d = gB + i; if (d < 2048u) cbB[d] = buf[4095u - i];
  }
}

// EXACT f32-only replacement for: fdiv_rn(max(i,0), max(uni,1e-6)) > 0.5
// (proof in R3/R4: i > 0.5f*max(uni,1e-6) is bit-identical to the reference)
__device__ __forceinline__ bool iou_gt(float2 a, float wa, float2 b, float wb) {
  float i = __fsub_rn(fminf(a.y, b.y), fmaxf(a.x, b.x));
  float uni = __fsub_rn(__fadd_rn(wa, wb), i);
  return i > __fmul_rn(0.5f, fmaxf(uni, 1e-6f));
}

__device__ __forceinline__ float2 decode_one(const float2* __restrict__ d2,
                                             const float2* __restrict__ a2,
                                             size_t base, u32 idx, float img) {
  float2 dd = d2[base + idx];
  float2 aa = a2[base + idx];
  float aw = __fsub_rn(aa.y, aa.x);
  float ac = __fadd_rn(aa.x, __fmul_rn(0.5f, aw));
  float dw = fminf(dd.y, 4.0f);
  float pc = __fadd_rn(__fmul_rn(dd.x, aw), ac);
  float pw = __fmul_rn(expf(dw), aw);
  float hx = __fmul_rn(0.5f, pw);
  float x1 = fminf(fmaxf(__fsub_rn(pc, hx), 0.0f), img);
  float x2 = fminf(fmaxf(__fadd_rn(pc, hx), 0.0f), img);
  return make_float2(x1, x2);
}

__device__ __forceinline__ u64 shflx64(u64 v, int j) {
  int lo = __shfl_xor((int)(u32)v, j, 64);
  int hi = __shfl_xor((int)(u32)(v >> 32), j, 64);
  return ((u64)(u32)hi << 32) | (u64)(u32)lo;
}

__device__ __forceinline__ void wave_ce(u64& e, int i, int k, int j, int lane) {
  u64 o = shflx64(e, j);
  bool low = ((lane & j) == 0);
  bool up = ((i & k) == 0);
  u64 mn = (o < e) ? o : e;
  u64 mx = (o < e) ? e : o;
  e = (low == up) ? mn : mx;
}

__device__ __forceinline__ void reg_ce(u64& a, u64& b, bool up) {
  u64 mn = (b < a) ? b : a;
  u64 mx = (b < a) ? a : b;
  a = up ? mn : mx;
  b = up ? mx : mn;
}

__device__ __forceinline__ void lds_ce(u64& e, u64 o, bool low, bool up) {
  u64 mn = (o < e) ? o : e;
  u64 mx = (o < e) ? e : o;
  e = (low == up) ? mn : mx;
}

// 3 blocks per image: h<2 sort the two A-halves; h==2 sorts B's first 1024 keys.
__global__ __launch_bounds__(512) void sorthalf_kernel(
    const u32* __restrict__ cntA, const u32* __restrict__ cntB,
    const u64* __restrict__ candA, const u64* __restrict__ candB,
    u64* __restrict__ sortA, u64* __restrict__ sortB) {
  __shared__ u64 ping[1024], pong[1024];   // 16 KB
  int b = blockIdx.x / 3, h = blockIdx.x % 3;
  int t = threadIdx.x, lane = t & 63;
  const u64* src;
  u64* dst;
  u32 lim;
  if (h < 2) {
    u32 S = cntA[b]; if (S > 2047u) S = 2047u;
    src = candA + (size_t)b * PRE_NMS + h * 1024;
    lim = (S > (u32)(h * 1024)) ? (S - (u32)(h * 1024)) : 0u;
    dst = sortA + (size_t)b * PRE_NMS + h * 1024;
  } else {
    u32 T = cntB[b]; if (T > 1024u) T = 1024u;   // T>1024 handled by rankdec fallback
    src = candB + (size_t)b * PRE_NMS;
    lim = T;
    dst = sortB + (size_t)b * 1024;
  }
  u64 e0 = ((u32)t < lim) ? src[t] : ~0ull;
  u64 e1 = ((u32)(t + 512) < lim) ? src[t + 512] : ~0ull;
  for (int k = 2; k <= 64; k <<= 1)
    for (int j = k >> 1; j >= 1; j >>= 1) {
      wave_ce(e0, t, k, j, lane);
      wave_ce(e1, t + 512, k, j, lane);
    }
  int pp = 0;
  for (int k = 128; k <= 1024; k <<= 1) {
    for (int j = k >> 1; j >= 64; j >>= 1) {
      if (j == 512) {
        reg_ce(e0, e1, true);              // k==1024 only: up for both halves
      } else {
        u64* buf = (pp & 1) ? pong : ping; ++pp;
        buf[t] = e0; buf[t + 512] = e1;
        __syncthreads();
        u64 o0 = buf[t ^ j];
        u64 o1 = buf[(t ^ j) + 512];
        bool low = ((t & j) == 0);
        lds_ce(e0, o0, low, ((t) & k) == 0);
        lds_ce(e1, o1, low, (((t + 512) & k)) == 0);
      }
    }
    for (int j = 32; j >= 1; j >>= 1) {
      wave_ce(e0, t, k, j, lane);
      wave_ce(e1, t + 512, k, j, lane);
    }
  }
  dst[t] = e0; dst[t + 512] = e1;
}

__device__ __forceinline__ u32 lowerbound(const u64* arr, u32 n, u64 k) {
  u32 lo = 0, hi = n;
  while (lo < hi) { u32 mid = (lo + hi) >> 1; if (arr[mid] < k) lo = mid + 1; else hi = mid; }
  return lo;
}

// rank (merge for A, pre-sorted for B) + decode + scatter boxes: 4 blocks/image
__global__ __launch_bounds__(512) void rankdec_kernel(
    const float* __restrict__ delta, const float* __restrict__ anchor,
    const int* __restrict__ imgp,
    const u32* __restrict__ cntA, const u32* __restrict__ cntB,
    const u64* __restrict__ sortA, const u64* __restrict__ candB,
    const u64* __restrict__ sortB, float2* __restrict__ boxg) {
  __shared__ u64 half_[PRE_NMS];   // 16 KB
  __shared__ u64 bkeys[PRE_NMS];   // 16 KB (fallback path only)

  int b = blockIdx.x >> 2, q = blockIdx.x & 3;
  int t = threadIdx.x;
  u32 S = cntA[b]; if (S > 2047u) S = 2047u;
  u32 T = cntB[b]; if (T > 2048u) T = 2048u;
  const u64* sA = sortA + (size_t)b * PRE_NMS;
  const u64* cB = candB + (size_t)b * PRE_NMS;
  for (int i = t; i < PRE_NMS; i += 512) half_[i] = sA[i];
  if (T > 1024u) {
    for (int i = t; i < PRE_NMS; i += 512) bkeys[i] = cB[i];
  }
  __syncthreads();

  int iv = imgp[0];
  float img = (iv > 0 && iv < 1000000) ? (float)iv : __int_as_float(iv);
  const float2* d2 = (const float2*)delta;
  const float2* a2 = (const float2*)anchor;
  size_t base = (size_t)b * NELEM;
  float2* bg = boxg + (size_t)b * PRE_NMS;

  {
    int p = q * 512 + t;
    u64 k = half_[p];
    if (k != ~0ull) {
      u32 rank;
      if (p < 1024) rank = (u32)p + lowerbound(half_ + 1024, 1024, k);
      else          rank = (u32)(p - 1024) + lowerbound(half_, 1024, k);
      bg[rank] = decode_one(d2, a2, base, (u32)k, img);
    }
  }
  if (T <= 1024u) {
    u32 idx = (u32)(q * 512 + t);
    if (idx < T) {
      u64 k = sortB[(size_t)b * 1024 + idx];
      u32 pos = S + idx;
      if (pos < 2048u) bg[pos] = decode_one(d2, a2, base, (u32)k, img);
    }
  } else {
    u32 idx = (u32)(q * 512 + t);
    if (idx < T) {
      u64 k = bkeys[idx];
      u32 cnt = 0;
      for (u32 j = 0; j < T; ++j) cnt += (bkeys[j] < k) ? 1u : 0u;
      u32 pos = S + cnt;
      if (pos < 2048u) bg[pos] = decode_one(d2, a2, base, (u32)k, img);
    }
  }
}

// chain: R7's validated TWO-barrier scheme (scan reads ONLY supm; all 16 waves
// mark after barrier A) + R11's validated cbox/cpid independent-array marking.
// 1024 threads; candidates (t, t+1024); chunks (wv, wv+16). No concurrent
// scan/mark, no scan-side kept loop.
__global__ __launch_bounds__(CTHR) void chain_kernel(
    const int* __restrict__ imgp, const float2* __restrict__ boxg,
    float* __restrict__ out) {
  __shared__ float2 box[PRE_NMS];      // 16 KB
  __shared__ float2 cbox[PRE_NMS];     // 16 KB center-sorted boxes
  __shared__ u16 cpid[PRE_NMS];        // 4 KB original pos of center-sorted slot
  __shared__ u32 bincnt[NSB], binstart[NSB + 1], binfill[NSB];
  __shared__ u32 supm[64];
  __shared__ float2 wbox[64];
  __shared__ u32 wrange[64];
  __shared__ u32 nkeptS, LcntS;
  __shared__ u32 keepw[NCH * 2];
  __shared__ u32 wpre[65];

  int b = blockIdx.x, t = threadIdx.x;
  int wv = t >> 6, lane = t & 63;

  int iv = imgp[0];
  float img = (iv > 0 && iv < 1000000) ? (float)iv : __int_as_float(iv);
  float sbin = (float)NSB / img;

  const float2* bg = boxg + (size_t)b * PRE_NMS;
  float2 bx0 = bg[t];
  float2 bx1 = bg[t + 1024];
  float wa0 = __fsub_rn(bx0.y, bx0.x);
  float wa1 = __fsub_rn(bx1.y, bx1.x);
  box[t] = bx0;
  box[t + 1024] = bx1;
  if (t < NSB) { bincnt[t] = 0u; binfill[t] = 0u; }
  if (t < 64) supm[t] = 0u;
  if (t == 0) LcntS = 0u;
  float ca0 = __fmul_rn(0.5f, __fadd_rn(bx0.x, bx0.y));
  float ca1 = __fmul_rn(0.5f, __fadd_rn(bx1.x, bx1.y));
  int bi0 = (int)(ca0 * sbin); if (bi0 > NSB - 1) bi0 = NSB - 1;
  int bi1 = (int)(ca1 * sbin); if (bi1 > NSB - 1) bi1 = NSB - 1;
  __syncthreads();

  // spatial counting sort of candidate centers into 256 bins
  atomicAdd(&bincnt[bi0], 1u);
  atomicAdd(&bincnt[bi1], 1u);
  __syncthreads();
  if (wv == 0) {
    u32 c0 = bincnt[lane * 4 + 0], c1 = bincnt[lane * 4 + 1];
    u32 c2 = bincnt[lane * 4 + 2], c3 = bincnt[lane * 4 + 3];
    u32 ssum = c0 + c1 + c2 + c3;
    u32 inc = ssum;
    for (int d = 1; d < 64; d <<= 1) {
      u32 v = __shfl_up(inc, d);
      if (lane >= d) inc += v;
    }
    u32 excl = inc - ssum;
    binstart[lane * 4 + 0] = excl;
    binstart[lane * 4 + 1] = excl + c0;
    binstart[lane * 4 + 2] = excl + c0 + c1;
    binstart[lane * 4 + 3] = excl + c0 + c1 + c2;
    if (lane == 63) binstart[NSB] = inc;
  }
  __syncthreads();
  {
    u32 s0 = binstart[bi0] + atomicAdd(&binfill[bi0], 1u);
    cpid[s0] = (u16)t;           cbox[s0] = bx0;
    u32 s1 = binstart[bi1] + atomicAdd(&binfill[bi1], 1u);
    cpid[s1] = (u16)(t + 1024);  cbox[s1] = bx1;
  }

  // in-chunk 64x64 exact adjacency rows, kept in registers
  u64 m0 = 0ull, m1 = 0ull;
  {
    int c0 = wv * 64, c1 = (wv + 16) * 64;
    for (int j = 0; j < 64; ++j) {
      float2 bb0 = box[c0 + j];
      float2 bb1 = box[c1 + j];
      float w0 = __fsub_rn(bb0.y, bb0.x);
      float w1 = __fsub_rn(bb1.y, bb1.x);
      if ((j != lane) & iou_gt(bx0, wa0, bb0, w0)) m0 |= 1ull << j;
      if ((j != lane) & iou_gt(bx1, wa1, bb1, w1)) m1 |= 1ull << j;
    }
  }
  __syncthreads();   // cpid/cbox complete

  // greedy NMS: scan chunk -> parallel windowed marking (two barriers/chunk)
  for (int ch = 0; ch < NCH; ++ch) {
    if (wv == (ch & 15)) {
      u32 supw = supm[ch * 2 + (lane >> 5)];
      bool mysup = (supw >> (lane & 31)) & 1u;
      u64 s = __ballot(mysup);
      u64 rem = ~s;
      u64 kept = 0ull;
      u64 myrow = (ch < 16) ? m0 : m1;
      u32 mlo = (u32)myrow, mhi = (u32)(myrow >> 32);
      while (rem) {                    // visit kept candidates only
        int i = __builtin_ctzll(rem);
        kept |= 1ull << i;
        u32 rlo = (u32)__builtin_amdgcn_readlane((int)mlo, i);
        u32 rhi = (u32)__builtin_amdgcn_readlane((int)mhi, i);
        u64 row = ((u64)rhi << 32) | (u64)rlo;
        rem &= ~(row | (1ull << i));
      }
      if ((kept >> lane) & 1ull) {
        float2 mb = (ch < 16) ? bx0 : bx1;
        // IoU>0.5 => suppressed box's center lies in [x1,x2]; +-0.25 margin
        // absorbs all f32 rounding and bin quantization (conservative).
        float loc_ = fmaxf(__fsub_rn(mb.x, 0.25f), 0.0f);
        float hic_ = __fadd_rn(mb.y, 0.25f);
        int blo = (int)(loc_ * sbin); if (blo > NSB - 1) blo = NSB - 1;
        int bhi = (int)(hic_ * sbin); if (bhi > NSB - 1) bhi = NSB - 1;
        u32 lo = binstart[blo];
        u32 hi = binstart[bhi + 1];
        u32 li = (u32)__popcll(kept & ((1ull << lane) - 1ull));
        wbox[li] = mb;
        wrange[li] = (lo << 16) | hi;
      }
      if (lane == 0) {
        keepw[ch * 2]     = (u32)kept;
        keepw[ch * 2 + 1] = (u32)(kept >> 32);
        nkeptS = (u32)__popcll(kept);
        LcntS += (u32)__popcll(kept);
      }
    }
    __syncthreads();                   // (A) scan results visible
    if (LcntS >= POST_NMS) {
      // outputs fully determined by the first 512 kept: zero undecided chunks
      int w2 = (ch + 1) * 2 + t;
      if (w2 < NCH * 2) keepw[w2] = 0u;
      break;
    }
    u32 nk = nkeptS;
    u32 cmin = (u32)(ch + 1) * 64u;    // only undecided chunks need marks
    for (u32 k2 = (u32)wv; k2 < nk; k2 += 16u) {
      float2 kb = wbox[k2];
      u32 rng = wrange[k2];
      u32 lo = rng >> 16, hi = rng & 0xFFFFu;
      float wbk = __fsub_rn(kb.y, kb.x);
      for (u32 idx = lo + (u32)lane; idx < hi; idx += 64u) {
        float2 bp = cbox[idx];          // independent load
        u32 p = cpid[idx];              // independent load (no chain)
        if (p >= cmin) {
          float wp = __fsub_rn(bp.y, bp.x);
          if (iou_gt(bp, wp, kb, wbk))
            atomicOr(&supm[p >> 5], 1u << (p & 31));
        }
      }
    }
    __syncthreads();                   // (B) marking visible before next scan
  }
  __syncthreads();                     // keepw zeroing (early-exit) visible

  // stable partition: kept first (ascending), then unkept (ascending)
  if (wv == 0) {
    u32 wvv = keepw[lane];
    u32 pc = __popc(wvv);
    u32 inc = pc;
    for (int d = 1; d < 64; d <<= 1) {
      u32 v = __shfl_up(inc, d);
      if (lane >= d) inc += v;
    }
    wpre[lane] = inc - pc;
    if (lane == 63) wpre[64] = inc;
  }
  __syncthreads();
  u32 K = wpre[64];
  size_t selOff = (size_t)BATCH * POST_NMS * 2;
  size_t valOff = selOff + (size_t)BATCH * POST_NMS;
#pragma unroll
  for (int r = 0; r < 2; ++r) {
    int p = t + CTHR * r;
    u32 w = p >> 5, bit = p & 31;
    u32 wvv = keepw[w];
    bool kp = (wvv >> bit) & 1u;
    u32 kpref = wpre[w] + __popc(wvv & ((1u << bit) - 1u));
    u32 rr = kp ? kpref : (K + ((u32)p - kpref));
    if (rr < POST_NMS) {
      float2 bxo = kp ? box[p] : make_float2(0.0f, 0.0f);
      size_t ob = (size_t)b * POST_NMS + rr;
      out[ob * 2 + 0] = bxo.x;
      out[ob * 2 + 1] = bxo.y;
      out[selOff + ob] = (float)p;
      out[valOff + ob] = kp ? 1.0f : 0.0f;
    }
  }
}

extern "C" void kernel_launch(void* const* d_in, const int* in_sizes, int n_in,
                              void* d_out, int out_size, void* d_ws, size_t ws_size,
                              hipStream_t stream) {
  const float* obj    = (const float*)d_in[0];
  const float* delta  = (const float*)d_in[1];
  const float* anchor = (const float*)d_in[2];
  const int*   imgp   = (const int*)d_in[3];
  float* out = (float*)d_out;

  unsigned char* w = (unsigned char*)d_ws;
  u32* hist  = (u32*)(w);
  u32* cntA  = (u32*)(w + OFF_CNTA);
  u32* cntB  = (u32*)(w + OFF_CNTB);
  u64* candA = (u64*)(w + OFF_CANDA);
  u64* candB = (u64*)(w + OFF_CANDB);
  u64* sortA = (u64*)(w + OFF_SORT);
  float2* boxg = (float2*)(w + OFF_BOXG);
  u64* sortB = (u64*)(w + OFF_SORTB);

  hipMemsetAsync(w, 0, OFF_ZERO, stream);   // re-init hist + cnts every call

  hist_kernel<<<dim3(256), dim3(256), 0, stream>>>(obj, hist);
  collect_kernel<<<dim3(512), dim3(256), 0, stream>>>(obj, hist, cntA, cntB, candA, candB);
  sorthalf_kernel<<<dim3(BATCH * 3), dim3(512), 0, stream>>>(cntA, cntB, candA, candB,
                                                             sortA, sortB);
  rankdec_kernel<<<dim3(BATCH * 4), dim3(512), 0, stream>>>(delta, anchor, imgp,
                                                            cntA, cntB, sortA, candB,
                                                            sortB, boxg);
  chain_kernel<<<dim3(BATCH), dim3(CTHR), 0, stream>>>(imgp, boxg, out);
}